// Round 3
// baseline (1029.857 us; speedup 1.0000x reference)
//
#include <hip/hip_runtime.h>
#include <hip/hip_bf16.h>

#define TPB  512
#define NBLK 256

typedef short    short8 __attribute__((ext_vector_type(8)));
typedef float    f32x4  __attribute__((ext_vector_type(4)));
typedef unsigned uint4v __attribute__((ext_vector_type(4)));

#define PROW 136            // panel row stride in shorts (272B = odd*16B)
#define PSZ  (128 * PROW)   // shorts per panel

__device__ __forceinline__ float fast_tanh(float z) {
    float e = __expf(2.0f * z);
    return 1.0f - 2.0f * __builtin_amdgcn_rcpf(e + 1.0f);
}

__device__ __forceinline__ unsigned short bf16_bits(float v) {
    __hip_bfloat16 b = __float2bfloat16(v);
    unsigned short s; __builtin_memcpy(&s, &b, 2);
    return s;
}

__device__ __forceinline__ unsigned pack_bf2(float lo, float hi) {
    return (unsigned)bf16_bits(lo) | ((unsigned)bf16_bits(hi) << 16);
}

// B-frag kk = bf16 pack of (vals[kk], vals[kk+4])  [sigma k-permutation]
__device__ __forceinline__ short8 packB(f32x4 lo, f32x4 hi) {
    uint4v u;
    u[0] = pack_bf2(lo[0], lo[1]);
    u[1] = pack_bf2(lo[2], lo[3]);
    u[2] = pack_bf2(hi[0], hi[1]);
    u[3] = pack_bf2(hi[2], hi[3]);
    return __builtin_bit_cast(short8, u);
}

// read back acc-position (nt,q) from packed B-frags (nt,q compile-time)
__device__ __forceinline__ float unpB(const short8* B, int nt, int q) {
    unsigned short us = B[nt & 3][((nt >> 2) << 2) | q];
    return __builtin_bit_cast(float, ((unsigned)us) << 16);
}

// 3 GEMMs D[n][s] += A*B sharing one A(weight)-panel pass.
__device__ __forceinline__ void gemm3T(const unsigned short* __restrict__ pnl,
                                       int c, int g,
                                       const short8 bZ[4], const short8 bX[4],
                                       const short8 bY[4],
                                       f32x4 accZ[8], f32x4 accX[8], f32x4 accY[8]) {
    #pragma unroll
    for (int kk = 0; kk < 4; kk++) {
        #pragma unroll
        for (int nt = 0; nt < 8; nt++) {
            const short8 af = *reinterpret_cast<const short8*>(
                pnl + (nt * 16 + c) * PROW + kk * 32 + g * 8);
            accZ[nt] = __builtin_amdgcn_mfma_f32_16x16x32_bf16(af, bZ[kk], accZ[nt], 0, 0, 0);
            accX[nt] = __builtin_amdgcn_mfma_f32_16x16x32_bf16(af, bX[kk], accX[nt], 0, 0, 0);
            accY[nt] = __builtin_amdgcn_mfma_f32_16x16x32_bf16(af, bY[kk], accY[nt], 0, 0, 0);
        }
    }
}

__global__ __launch_bounds__(TPB, 2) void mlp_mfma_kernel(
    const float* __restrict__ X,
    const float* __restrict__ gW1, const float* __restrict__ gB1,
    const float* __restrict__ gW2, const float* __restrict__ gB2,
    const float* __restrict__ gW3, const float* __restrict__ gB3,
    const float* __restrict__ gW4, const float* __restrict__ gB4,
    float* __restrict__ out, int N)
{
    // 4 weight panels as MFMA A-operands: [n][sigma(k)], row stride 136 shorts.
    // 0: W2 fwd (W2[f][n])  1: W2 bwd (W2[n][f])  2: W3 fwd  3: W3 bwd
    __shared__ alignas(16) unsigned short sPanel[4 * PSZ];      // 139264 B
    __shared__ alignas(16) float sParam[7 * 128];               // w1t w1x w1y b1 b2 b3 w4

    const int tid = threadIdx.x;
    for (int idx = tid; idx < 4 * 128 * 128; idx += TPB) {
        int p = idx >> 14, e = idx & 16383, n = e >> 7, pp = e & 127;
        int kk = pp >> 5, gg = (pp >> 3) & 3, jj = pp & 7;
        int f = ((((jj >> 2) << 2) | kk) << 4) | (gg << 2) | (jj & 3);  // invsigma
        const float* Wsrc = (p < 2) ? gW2 : gW3;
        float v = (p & 1) ? Wsrc[n * 128 + f] : Wsrc[f * 128 + n];
        sPanel[p * PSZ + n * PROW + pp] = bf16_bits(v);
    }
    if (tid < 128) {
        sParam[0 * 128 + tid] = gW1[tid];
        sParam[1 * 128 + tid] = gW1[128 + tid];
        sParam[2 * 128 + tid] = gW1[256 + tid];
        sParam[3 * 128 + tid] = gB1[tid];
        sParam[4 * 128 + tid] = gB2[tid];
        sParam[5 * 128 + tid] = gB3[tid];
        sParam[6 * 128 + tid] = gW4[tid];
    }
    __syncthreads();

    const int lane = tid & 63;
    const int wave = tid >> 6;
    const int c = lane & 15, g = lane >> 4;
    const int fb = g << 2;   // lane's feature offset within each 16-row tile
    const unsigned short* const pW2f = sPanel;
    const unsigned short* const pW2b = sPanel + PSZ;
    const unsigned short* const pW3f = sPanel + 2 * PSZ;
    const unsigned short* const pW3b = sPanel + 3 * PSZ;
    const float b4 = gB4[0];

    const int tiles = N >> 4;
    for (int t = blockIdx.x * 8 + wave; t < tiles; t += NBLK * 8) {
        const int sbase = t << 4;
        const float* xp = X + (long)(sbase + c) * 3;
        const float xt = xp[0], xx = xp[1], xy = xp[2];

        short8 h1B[4], x1B[4], y1B[4];
        // ---- Phase A: z1/h1 (fp32) + tangent seeds th1* = (1-h1^2)*W1[x|y] ----
        {
            f32x4 hz[8], tx[8], ty[8];
            #pragma unroll
            for (int nt = 0; nt < 8; nt++) {
                const int f0 = nt * 16 + fb;
                f32x4 wt = *(const f32x4*)(sParam + 0 * 128 + f0);
                f32x4 wx = *(const f32x4*)(sParam + 1 * 128 + f0);
                f32x4 wy = *(const f32x4*)(sParam + 2 * 128 + f0);
                f32x4 bb = *(const f32x4*)(sParam + 3 * 128 + f0);
                #pragma unroll
                for (int q = 0; q < 4; q++) {
                    float z = fmaf(xt, wt[q], fmaf(xx, wx[q], fmaf(xy, wy[q], bb[q])));
                    float h = fast_tanh(z);
                    float a = 1.f - h * h;
                    hz[nt][q] = h; tx[nt][q] = a * wx[q]; ty[nt][q] = a * wy[q];
                }
            }
            #pragma unroll
            for (int kk = 0; kk < 4; kk++) {
                h1B[kk] = packB(hz[kk], hz[kk + 4]);
                x1B[kk] = packB(tx[kk], tx[kk + 4]);
                y1B[kk] = packB(ty[kk], ty[kk + 4]);
            }
        }

        f32x4 accZ[8], accX[8], accY[8];
        // ---- Phase B: z2 = W2^T h1 (+b2) ; tz2x ; tz2y ----
        #pragma unroll
        for (int nt = 0; nt < 8; nt++) {
            accZ[nt] = *(const f32x4*)(sParam + 4 * 128 + nt * 16 + fb);
            accX[nt] = f32x4{0.f, 0.f, 0.f, 0.f};
            accY[nt] = f32x4{0.f, 0.f, 0.f, 0.f};
        }
        gemm3T(pW2f, c, g, h1B, x1B, y1B, accZ, accX, accY);

        // ---- Phase C: h2, th2x, th2y (packed = state + next operands) ----
        short8 h2B[4], x2B[4], y2B[4];
        {
            f32x4 hz[8], tx[8], ty[8];
            #pragma unroll
            for (int nt = 0; nt < 8; nt++) {
                #pragma unroll
                for (int q = 0; q < 4; q++) {
                    float h = fast_tanh(accZ[nt][q]);
                    float a = 1.f - h * h;
                    hz[nt][q] = h;
                    tx[nt][q] = a * accX[nt][q];
                    ty[nt][q] = a * accY[nt][q];
                }
            }
            #pragma unroll
            for (int kk = 0; kk < 4; kk++) {
                h2B[kk] = packB(hz[kk], hz[kk + 4]);
                x2B[kk] = packB(tx[kk], tx[kk + 4]);
                y2B[kk] = packB(ty[kk], ty[kk + 4]);
            }
        }

        // ---- Phase D: z3 ; tz3x ; tz3y ----
        #pragma unroll
        for (int nt = 0; nt < 8; nt++) {
            accZ[nt] = *(const f32x4*)(sParam + 5 * 128 + nt * 16 + fb);
            accX[nt] = f32x4{0.f, 0.f, 0.f, 0.f};
            accY[nt] = f32x4{0.f, 0.f, 0.f, 0.f};
        }
        gemm3T(pW3f, c, g, h2B, x2B, y2B, accZ, accX, accY);

        // ---- Phase E: h3, value output, d3, td3x, td3y ----
        short8 d3B[4], x3B[4], y3B[4];
        {
            float cp = 0.f;
            f32x4 dz[8], tx[8], ty[8];
            #pragma unroll
            for (int nt = 0; nt < 8; nt++) {
                f32x4 w4v = *(const f32x4*)(sParam + 6 * 128 + nt * 16 + fb);
                #pragma unroll
                for (int q = 0; q < 4; q++) {
                    float h = fast_tanh(accZ[nt][q]);
                    float a = 1.f - h * h;
                    cp = fmaf(h, w4v[q], cp);
                    dz[nt][q] = w4v[q] * a;
                    tx[nt][q] = -2.f * w4v[q] * h * (a * accX[nt][q]);
                    ty[nt][q] = -2.f * w4v[q] * h * (a * accY[nt][q]);
                }
            }
            #pragma unroll
            for (int kk = 0; kk < 4; kk++) {
                d3B[kk] = packB(dz[kk], dz[kk + 4]);
                x3B[kk] = packB(tx[kk], tx[kk + 4]);
                y3B[kk] = packB(ty[kk], ty[kk + 4]);
            }
            cp += __shfl_xor(cp, 16, 64);
            cp += __shfl_xor(cp, 32, 64);
            if (lane < 16) out[sbase + lane] = cp + b4;
        }

        // ---- Phase F: u2 = W3 d3 ; tu2x ; tu2y ----
        #pragma unroll
        for (int nt = 0; nt < 8; nt++) {
            accZ[nt] = f32x4{0.f, 0.f, 0.f, 0.f};
            accX[nt] = f32x4{0.f, 0.f, 0.f, 0.f};
            accY[nt] = f32x4{0.f, 0.f, 0.f, 0.f};
        }
        gemm3T(pW3b, c, g, d3B, x3B, y3B, accZ, accX, accY);

        // ---- Phase G: d2, td2x, td2y ----
        short8 d2B[4], xdB[4], ydB[4];
        {
            f32x4 dz[8], tx[8], ty[8];
            #pragma unroll
            for (int nt = 0; nt < 8; nt++) {
                #pragma unroll
                for (int q = 0; q < 4; q++) {
                    float h   = unpB(h2B, nt, q);
                    float thx = unpB(x2B, nt, q);
                    float thy = unpB(y2B, nt, q);
                    float a   = 1.f - h * h;
                    float u2  = accZ[nt][q];
                    dz[nt][q] = u2 * a;
                    tx[nt][q] = accX[nt][q] * a - 2.f * u2 * h * thx;
                    ty[nt][q] = accY[nt][q] * a - 2.f * u2 * h * thy;
                }
            }
            #pragma unroll
            for (int kk = 0; kk < 4; kk++) {
                d2B[kk] = packB(dz[kk], dz[kk + 4]);
                xdB[kk] = packB(tx[kk], tx[kk + 4]);
                ydB[kk] = packB(ty[kk], ty[kk + 4]);
            }
        }

        // ---- Phase H: u1 = W2 d2 ; tu1x ; tu1y ----
        #pragma unroll
        for (int nt = 0; nt < 8; nt++) {
            accZ[nt] = f32x4{0.f, 0.f, 0.f, 0.f};
            accX[nt] = f32x4{0.f, 0.f, 0.f, 0.f};
            accY[nt] = f32x4{0.f, 0.f, 0.f, 0.f};
        }
        gemm3T(pW2b, c, g, d2B, xdB, ydB, accZ, accX, accY);

        // ---- Phase I: d1, gradient + HVP projections ----
        {
            float gt = 0.f, gx = 0.f, gy = 0.f, hx = 0.f, hy = 0.f;
            #pragma unroll
            for (int nt = 0; nt < 8; nt++) {
                const int f0 = nt * 16 + fb;
                f32x4 wt = *(const f32x4*)(sParam + 0 * 128 + f0);
                f32x4 wx = *(const f32x4*)(sParam + 1 * 128 + f0);
                f32x4 wy = *(const f32x4*)(sParam + 2 * 128 + f0);
                #pragma unroll
                for (int q = 0; q < 4; q++) {
                    float h  = unpB(h1B, nt, q);
                    float a  = 1.f - h * h;
                    float u1 = accZ[nt][q];
                    float d1 = u1 * a;
                    gt = fmaf(d1, wt[q], gt);
                    gx = fmaf(d1, wx[q], gx);
                    gy = fmaf(d1, wy[q], gy);
                    float thx = a * wx[q], thy = a * wy[q];
                    float tdx = accX[nt][q] * a - 2.f * u1 * h * thx;
                    float tdy = accY[nt][q] * a - 2.f * u1 * h * thy;
                    hx = fmaf(tdx, wx[q], hx);
                    hy = fmaf(tdy, wy[q], hy);
                }
            }
            gt += __shfl_xor(gt, 16, 64); gt += __shfl_xor(gt, 32, 64);
            gx += __shfl_xor(gx, 16, 64); gx += __shfl_xor(gx, 32, 64);
            gy += __shfl_xor(gy, 16, 64); gy += __shfl_xor(gy, 32, 64);
            hx += __shfl_xor(hx, 16, 64); hx += __shfl_xor(hx, 32, 64);
            hy += __shfl_xor(hy, 16, 64); hy += __shfl_xor(hy, 32, 64);
            if (lane < 16) {
                long s = sbase + lane;
                out[(long)N + s]  = gt;
                out[2L * N + s]   = gx;
                out[3L * N + s]   = gy;
                out[4L * N + s]   = hx;
                out[5L * N + s]   = hy;
            }
        }
    }
}

extern "C" void kernel_launch(void* const* d_in, const int* in_sizes, int n_in,
                              void* d_out, int out_size, void* d_ws, size_t ws_size,
                              hipStream_t stream) {
    const float* X  = (const float*)d_in[0];
    const float* W1 = (const float*)d_in[1];
    const float* B1 = (const float*)d_in[2];
    const float* W2 = (const float*)d_in[3];
    const float* B2 = (const float*)d_in[4];
    const float* W3 = (const float*)d_in[5];
    const float* B3 = (const float*)d_in[6];
    const float* W4 = (const float*)d_in[7];
    const float* B4 = (const float*)d_in[8];
    float* out = (float*)d_out;
    const int N = in_sizes[0] / 3;

    mlp_mfma_kernel<<<NBLK, TPB, 0, stream>>>(X, W1, B1, W2, B2, W3, B3, W4, B4, out, N);
}